// Round 8
// baseline (1372.662 us; speedup 1.0000x reference)
//
#include <hip/hip_runtime.h>
#include <cstdint>
#include <cstddef>

#define T_DIM 4096
#define H_DIM 4096
#define I_DIM 11008

typedef int v4i  __attribute__((ext_vector_type(4)));
typedef int v16i __attribute__((ext_vector_type(16)));

// ---------------------------------------------------------------------------
// async global->LDS copy, 16B per lane (global_load_lds_dwordx4)
// ---------------------------------------------------------------------------
__device__ __forceinline__ void async_copy16(const void* g, void* l) {
  __builtin_amdgcn_global_load_lds(
      (const __attribute__((address_space(1))) void*)g,
      (__attribute__((address_space(3))) void*)l, 16, 0, 0);
}

// ---------------------------------------------------------------------------
// int32 -> int8 pack (values already in [-127,127])
// ---------------------------------------------------------------------------
__global__ void pack_i8(const int4* __restrict__ src, char4* __restrict__ dst, int n4) {
  int stride = gridDim.x * blockDim.x;
  for (int i = blockIdx.x * blockDim.x + threadIdx.x; i < n4; i += stride) {
    int4 v = src[i];
    char4 c;
    c.x = (char)v.x; c.y = (char)v.y; c.z = (char)v.z; c.w = (char)v.w;
    dst[i] = c;
  }
}

__global__ void zero_u32(unsigned* __restrict__ p, int n) {
  int i = blockIdx.x * blockDim.x + threadIdx.x;
  if (i < n) p[i] = 0u;
}

// ---------------------------------------------------------------------------
// GEMM1: gu = x_q @ w_gate_up^T (gate col n / up col I+n share the A tile),
// epilogue y = silu(gate)*up, per-row absmax via shfl + atomicMax.
// 128x128 tile, BK=64, 4 waves each 64x64 gate + 64x64 up.
// R8: MFMA 32x32x32 i8 (4404 vs 3944 TOPS, half the issue slots). Fragment:
// lane holds row=(lane&31) of the 32-row block, 16B k-chunk (kh<<1)|(lane>>5)
// of the 64B K-row; physical chunk = logical ^ ((r>>1)&3) (same staging
// swizzle as before, LDS traffic unchanged: 12 ds_read_b128/wave/phase).
// Schedule: R6-verified m201-ordered counted-vmcnt depth-2 pipeline.
// ---------------------------------------------------------------------------
__global__ __launch_bounds__(256, 2)
void gemm1_silu(const int8_t* __restrict__ x8,
                const int8_t* __restrict__ wgu8,
                const float* __restrict__ x_scale,
                const float* __restrict__ s_wgu,
                float* __restrict__ y,
                unsigned* __restrict__ rowmax) {
  __shared__ __align__(16) char lds0[24576];
  __shared__ __align__(16) char lds1[24576];
  __shared__ __align__(16) char lds2[24576];

  const int tid = threadIdx.x;
  const int wave = tid >> 6, lane = tid & 63;
  const int wm = wave >> 1, wn = wave & 1;

  // Supertile XCD swizzle (R3, verified): 86x32 grid = 2752 blocks, 344/XCD.
  const unsigned bid = blockIdx.y * gridDim.x + blockIdx.x;
  const unsigned xcd = bid & 7;
  const unsigned l   = bid >> 3;        // 0..343
  const unsigned s   = l >> 5;          // supertile 0..10
  const unsigned r   = l - (s << 5);    // 0..31 (0..23 in the last)
  const int m0 = (int)(xcd * 4 + (r & 3)) * 128;
  const int n0 = (int)(s * 8 + (r >> 2)) * 128;

  v16i accg[2][2], accu[2][2];
#pragma unroll
  for (int i = 0; i < 2; i++)
#pragma unroll
    for (int j = 0; j < 2; j++) {
#pragma unroll
      for (int k = 0; k < 16; k++) { accg[i][j][k] = 0; accu[i][j][k] = 0; }
    }

  const int8_t* Ab  = x8 + (size_t)m0 * H_DIM;
  const int8_t* Bgb = wgu8 + (size_t)n0 * H_DIM;
  const int8_t* Bub = wgu8 + ((size_t)I_DIM + (size_t)n0) * H_DIM;

  // hoisted per-lane staging offsets (K-invariant)
  const int sr0 = wave * 16 + (lane >> 2);
  const int sr1 = (4 + wave) * 16 + (lane >> 2);
  const int sc0 = (lane & 3) ^ ((sr0 >> 1) & 3);
  const int sc1 = (lane & 3) ^ ((sr1 >> 1) & 3);
  const size_t vo0 = (size_t)sr0 * H_DIM + (size_t)sc0 * 16;
  const size_t vo1 = (size_t)sr1 * H_DIM + (size_t)sc1 * 16;
  const int ldsSeg0 = wave * 1024;
  const int ldsSeg1 = (4 + wave) * 1024;

  // hoisted per-lane 32x32 fragment byte offsets (kh=0; kh=1 toggles bit 5:
  // c = ((kh<<1)|g)^s -> byte5 = kh^s1, so addr(kh=1) = addr(kh=0) ^ 32)
  const int g5 = lane >> 5;
  int aoff[2], boff[2];
#pragma unroll
  for (int mi = 0; mi < 2; mi++) {
    const int rr = wm * 64 + mi * 32 + (lane & 31);
    aoff[mi] = rr * 64 + ((g5 ^ ((rr >> 1) & 3)) << 4);
  }
#pragma unroll
  for (int nj = 0; nj < 2; nj++) {
    const int rr = wn * 64 + nj * 32 + (lane & 31);
    boff[nj] = rr * 64 + ((g5 ^ ((rr >> 1) & 3)) << 4);
  }

#define G1_STAGE(L, T)                                                      \
  {                                                                         \
    const int8_t* A_ = Ab + ((size_t)(T) << 6);                             \
    const int8_t* G_ = Bgb + ((size_t)(T) << 6);                            \
    const int8_t* U_ = Bub + ((size_t)(T) << 6);                            \
    async_copy16(A_ + vo0, (L) + ldsSeg0);                                  \
    async_copy16(A_ + vo1, (L) + ldsSeg1);                                  \
    async_copy16(G_ + vo0, (L) + 8192 + ldsSeg0);                           \
    async_copy16(G_ + vo1, (L) + 8192 + ldsSeg1);                           \
    async_copy16(U_ + vo0, (L) + 16384 + ldsSeg0);                          \
    async_copy16(U_ + vo1, (L) + 16384 + ldsSeg1);                          \
  }

#define G1_PHASE(Lc, Ls, T2, DOSTAGE, VM)                                   \
  {                                                                         \
    v4i a[2][2], bg[2][2], bu[2][2];                                        \
    _Pragma("unroll")                                                       \
    for (int mi = 0; mi < 2; mi++) {                                        \
      a[mi][0] = *(const v4i*)((Lc) + aoff[mi]);                            \
      a[mi][1] = *(const v4i*)((Lc) + (aoff[mi] ^ 32));                     \
    }                                                                       \
    _Pragma("unroll")                                                       \
    for (int nj = 0; nj < 2; nj++) {                                        \
      bg[nj][0] = *(const v4i*)((Lc) + 8192 + boff[nj]);                    \
      bg[nj][1] = *(const v4i*)((Lc) + 8192 + (boff[nj] ^ 32));             \
      bu[nj][0] = *(const v4i*)((Lc) + 16384 + boff[nj]);                   \
      bu[nj][1] = *(const v4i*)((Lc) + 16384 + (boff[nj] ^ 32));            \
    }                                                                       \
    if (DOSTAGE) G1_STAGE(Ls, T2);                                          \
    __builtin_amdgcn_s_setprio(1);                                          \
    _Pragma("unroll")                                                       \
    for (int kh = 0; kh < 2; kh++)                                          \
      _Pragma("unroll")                                                     \
      for (int mi = 0; mi < 2; mi++)                                        \
        _Pragma("unroll")                                                   \
        for (int nj = 0; nj < 2; nj++) {                                    \
          accg[mi][nj] = __builtin_amdgcn_mfma_i32_32x32x32_i8(             \
              a[mi][kh], bg[nj][kh], accg[mi][nj], 0, 0, 0);                \
          accu[mi][nj] = __builtin_amdgcn_mfma_i32_32x32x32_i8(             \
              a[mi][kh], bu[nj][kh], accu[mi][nj], 0, 0, 0);                \
        }                                                                   \
    __builtin_amdgcn_s_setprio(0);                                          \
    asm volatile("s_waitcnt " VM ::: "memory");                             \
    __builtin_amdgcn_s_barrier();                                           \
  }

  G1_STAGE(lds0, 0);
  G1_STAGE(lds1, 1);
  asm volatile("s_waitcnt vmcnt(6)" ::: "memory");
  __builtin_amdgcn_s_barrier();

  // 64 K-tiles: phases 0..59 in-loop (20 x 3), 60..63 peeled with static VM.
  for (int t = 0; t < 60; t += 3) {
    G1_PHASE(lds0, lds2, t + 2, 1, "vmcnt(6)")
    G1_PHASE(lds1, lds0, t + 3, 1, "vmcnt(6)")
    G1_PHASE(lds2, lds1, t + 4, 1, "vmcnt(6)")
  }
  G1_PHASE(lds0, lds2, 62, 1, "vmcnt(6)")   // t=60
  G1_PHASE(lds1, lds0, 63, 1, "vmcnt(6)")   // t=61
  G1_PHASE(lds2, lds0,  0, 0, "vmcnt(0)")   // t=62: no stage, drain tile 63
  G1_PHASE(lds0, lds0,  0, 0, "vmcnt(0)")   // t=63: final
#undef G1_PHASE
#undef G1_STAGE

  // Epilogue. 32x32 C/D layout (verified, dtype-independent):
  // col = lane&31, row = (reg&3) + 8*(reg>>2) + 4*(lane>>5).
  const int col = lane & 31;
  const int hh  = (lane >> 5) * 4;
#pragma unroll
  for (int mi = 0; mi < 2; mi++) {
#pragma unroll
    for (int tr = 0; tr < 16; tr++) {
      const int gr = m0 + wm * 64 + mi * 32 + (tr & 3) + 8 * (tr >> 2) + hh;
      const float sx = x_scale[gr];
      float vmax = 0.f;
#pragma unroll
      for (int nj = 0; nj < 2; nj++) {
        const int gc = n0 + wn * 64 + nj * 32 + col;
        float g = (float)accg[mi][nj][tr] * sx * s_wgu[gc];
        float u = (float)accu[mi][nj][tr] * sx * s_wgu[I_DIM + gc];
        float yv = (g / (1.f + expf(-g))) * u;   // silu(g) * u
        y[(size_t)gr * I_DIM + gc] = yv;
        vmax = fmaxf(vmax, fabsf(yv));
      }
      // reduce across the 32 lanes of this half-wave (all offsets < 32 keep
      // lanes within their half)
#pragma unroll
      for (int off = 1; off < 32; off <<= 1)
        vmax = fmaxf(vmax, __shfl_xor(vmax, off, 64));
      if (col == 0) atomicMax(&rowmax[gr], __float_as_uint(vmax));
    }
  }
}

// ---------------------------------------------------------------------------
// quantize y -> int8 with dynamic per-row scale s2 = max(|y|,1e-8)/127
// jnp.round == round-half-even == rintf
// R8: 32-bit const divide (magic-mul) instead of 64-bit div per thread.
// ---------------------------------------------------------------------------
__global__ void quantize_y(const float* __restrict__ y,
                           const unsigned* __restrict__ rowmax,
                           int8_t* __restrict__ yq) {
  const int N4 = (int)((size_t)T_DIM * I_DIM / 4);   // 11,272,192
  int gid = blockIdx.x * blockDim.x + threadIdx.x;
  if (gid >= N4) return;
  int row = gid / (I_DIM / 4);     // 32-bit const div -> magic multiply
  size_t base = (size_t)gid * 4;   // I_DIM % 4 == 0, packs never cross rows
  float inv = 127.f / fmaxf(__uint_as_float(rowmax[row]), 1e-8f);
  float4 v = *(const float4*)(y + base);
  char4 q;
  q.x = (char)(int)fminf(127.f, fmaxf(-128.f, rintf(v.x * inv)));
  q.y = (char)(int)fminf(127.f, fmaxf(-128.f, rintf(v.y * inv)));
  q.z = (char)(int)fminf(127.f, fmaxf(-128.f, rintf(v.z * inv)));
  q.w = (char)(int)fminf(127.f, fmaxf(-128.f, rintf(v.w * inv)));
  *(char4*)(yq + base) = q;
}

// ---------------------------------------------------------------------------
// GEMM2: out = (y_q @ w_down^T) * s2[row] * s_w_down[col]
// 128m x 256n tile (R7), BK=64; R8: MFMA 32x32x32 i8. Per wave 64m x 128n =
// 2x4 32x32 blocks x 2 k-halves = 16 MFMA/phase. Same staging/pipeline.
// ---------------------------------------------------------------------------
__global__ __launch_bounds__(256, 2)
void gemm2_scaled(const int8_t* __restrict__ yq8,
                  const int8_t* __restrict__ wd8,
                  const unsigned* __restrict__ rowmax,
                  const float* __restrict__ s_wd,
                  float* __restrict__ out) {
  __shared__ __align__(16) char lds0[24576];
  __shared__ __align__(16) char lds1[24576];
  __shared__ __align__(16) char lds2[24576];

  const int tid = threadIdx.x;
  const int wave = tid >> 6, lane = tid & 63;
  const int wm = wave >> 1, wn = wave & 1;

  // XCD swizzle: grid = 16n x 32m = 512 blocks, 64/XCD = 4m x 16n.
  const unsigned bid = blockIdx.y * gridDim.x + blockIdx.x;
  const unsigned xcd = bid & 7;
  const unsigned l   = bid >> 3;            // 0..63
  const int m0 = (int)(xcd * 4 + (l & 3)) * 128;
  const int n0 = (int)(l >> 2) * 256;       // 0..15 * 256

  v16i acc[2][4];
#pragma unroll
  for (int i = 0; i < 2; i++)
#pragma unroll
    for (int j = 0; j < 4; j++) {
#pragma unroll
      for (int k = 0; k < 16; k++) acc[i][j][k] = 0;
    }

  const int8_t* Ab = yq8 + (size_t)m0 * I_DIM;
  const int8_t* Bb = wd8 + (size_t)n0 * I_DIM;

  // staging offsets: A tile 128 rows (2 loads/lane), B tile 256 rows (4).
  const int lrow = lane >> 2;
  const int lchk = lane & 3;
  int srA[2], srB[4];
  srA[0] = wave * 16 + lrow;        srA[1] = (4 + wave) * 16 + lrow;
#pragma unroll
  for (int q = 0; q < 4; q++) srB[q] = (q * 4 + wave) * 16 + lrow;
  size_t voA[2], voB[4];
#pragma unroll
  for (int q = 0; q < 2; q++)
    voA[q] = (size_t)srA[q] * I_DIM + (size_t)(lchk ^ ((srA[q] >> 1) & 3)) * 16;
#pragma unroll
  for (int q = 0; q < 4; q++)
    voB[q] = (size_t)srB[q] * I_DIM + (size_t)(lchk ^ ((srB[q] >> 1) & 3)) * 16;
  const int segA0 = wave * 1024, segA1 = (4 + wave) * 1024;

  // hoisted 32x32 fragment byte offsets (kh toggles bit 5)
  const int g5 = lane >> 5;
  int aoff[2], boff[4];
#pragma unroll
  for (int mi = 0; mi < 2; mi++) {
    const int rr = wm * 64 + mi * 32 + (lane & 31);
    aoff[mi] = rr * 64 + ((g5 ^ ((rr >> 1) & 3)) << 4);
  }
#pragma unroll
  for (int nj = 0; nj < 4; nj++) {
    const int rr = wn * 128 + nj * 32 + (lane & 31);
    boff[nj] = rr * 64 + ((g5 ^ ((rr >> 1) & 3)) << 4);
  }

#define G2_STAGE(L, T)                                                      \
  {                                                                         \
    const int8_t* A_ = Ab + ((size_t)(T) << 6);                             \
    const int8_t* B_ = Bb + ((size_t)(T) << 6);                             \
    async_copy16(A_ + voA[0], (L) + segA0);                                 \
    async_copy16(A_ + voA[1], (L) + segA1);                                 \
    async_copy16(B_ + voB[0], (L) + 8192 + segA0);                          \
    async_copy16(B_ + voB[1], (L) + 8192 + segA1);                          \
    async_copy16(B_ + voB[2], (L) + 8192 + segA0 + 8192);                   \
    async_copy16(B_ + voB[3], (L) + 8192 + segA1 + 8192);                   \
  }

#define G2_PHASE(Lc, Ls, T2, DOSTAGE, VM)                                   \
  {                                                                         \
    v4i a[2][2], b[4][2];                                                   \
    _Pragma("unroll")                                                       \
    for (int mi = 0; mi < 2; mi++) {                                        \
      a[mi][0] = *(const v4i*)((Lc) + aoff[mi]);                            \
      a[mi][1] = *(const v4i*)((Lc) + (aoff[mi] ^ 32));                     \
    }                                                                       \
    _Pragma("unroll")                                                       \
    for (int nj = 0; nj < 4; nj++) {                                        \
      b[nj][0] = *(const v4i*)((Lc) + 8192 + boff[nj]);                     \
      b[nj][1] = *(const v4i*)((Lc) + 8192 + (boff[nj] ^ 32));              \
    }                                                                       \
    if (DOSTAGE) G2_STAGE(Ls, T2);                                          \
    __builtin_amdgcn_s_setprio(1);                                          \
    _Pragma("unroll")                                                       \
    for (int kh = 0; kh < 2; kh++)                                          \
      _Pragma("unroll")                                                     \
      for (int mi = 0; mi < 2; mi++)                                        \
        _Pragma("unroll")                                                   \
        for (int nj = 0; nj < 4; nj++)                                      \
          acc[mi][nj] = __builtin_amdgcn_mfma_i32_32x32x32_i8(              \
              a[mi][kh], b[nj][kh], acc[mi][nj], 0, 0, 0);                  \
    __builtin_amdgcn_s_setprio(0);                                          \
    asm volatile("s_waitcnt " VM ::: "memory");                             \
    __builtin_amdgcn_s_barrier();                                           \
  }

  G2_STAGE(lds0, 0);
  G2_STAGE(lds1, 1);
  asm volatile("s_waitcnt vmcnt(6)" ::: "memory");
  __builtin_amdgcn_s_barrier();

  // 172 K-tiles: phases 0..167 in-loop (56 x 3), 168..171 peeled.
  for (int t = 0; t < 168; t += 3) {
    G2_PHASE(lds0, lds2, t + 2, 1, "vmcnt(6)")
    G2_PHASE(lds1, lds0, t + 3, 1, "vmcnt(6)")
    G2_PHASE(lds2, lds1, t + 4, 1, "vmcnt(6)")
  }
  G2_PHASE(lds0, lds2, 170, 1, "vmcnt(6)")  // t=168
  G2_PHASE(lds1, lds0, 171, 1, "vmcnt(6)")  // t=169
  G2_PHASE(lds2, lds0,   0, 0, "vmcnt(0)")  // t=170: drain tile 171
  G2_PHASE(lds0, lds0,   0, 0, "vmcnt(0)")  // t=171: final
#undef G2_PHASE
#undef G2_STAGE

  // Epilogue, 32x32 C/D layout.
  const int col = lane & 31;
  const int hh  = (lane >> 5) * 4;
#pragma unroll
  for (int mi = 0; mi < 2; mi++) {
#pragma unroll
    for (int tr = 0; tr < 16; tr++) {
      const int gr = m0 + wm * 64 + mi * 32 + (tr & 3) + 8 * (tr >> 2) + hh;
      const float s2 = fmaxf(__uint_as_float(rowmax[gr]), 1e-8f) / 127.f;
#pragma unroll
      for (int nj = 0; nj < 4; nj++) {
        const int gc = n0 + wn * 128 + nj * 32 + col;
        out[(size_t)gr * H_DIM + gc] = (float)acc[mi][nj][tr] * s2 * s_wd[gc];
      }
    }
  }
}

// ---------------------------------------------------------------------------
// launch
// ---------------------------------------------------------------------------
extern "C" void kernel_launch(void* const* d_in, const int* in_sizes, int n_in,
                              void* d_out, int out_size, void* d_ws, size_t ws_size,
                              hipStream_t stream) {
  const int*   x_q     = (const int*)d_in[0];
  const float* x_scale = (const float*)d_in[1];
  const int*   w_gu    = (const int*)d_in[2];
  const float* s_wgu   = (const float*)d_in[3];
  const int*   w_d     = (const int*)d_in[4];
  const float* s_wd    = (const float*)d_in[5];
  float* out = (float*)d_out;

  // workspace layout (bytes)
  char* ws = (char*)d_ws;
  const size_t SZ_X8   = (size_t)T_DIM * H_DIM;          //  16,777,216
  const size_t SZ_WGU8 = (size_t)2 * I_DIM * H_DIM;      //  90,177,536
  const size_t SZ_WD8  = (size_t)H_DIM * I_DIM;          //  45,088,768
  const size_t SZ_Y    = (size_t)T_DIM * I_DIM * 4;      // 180,355,072
  const size_t SZ_YQ   = (size_t)T_DIM * I_DIM;          //  45,088,768

  int8_t*   x8     = (int8_t*)ws;
  int8_t*   wgu8   = (int8_t*)(ws + SZ_X8);
  int8_t*   wd8    = (int8_t*)(ws + SZ_X8 + SZ_WGU8);
  float*    y      = (float*)(ws + SZ_X8 + SZ_WGU8 + SZ_WD8);
  int8_t*   yq8    = (int8_t*)(ws + SZ_X8 + SZ_WGU8 + SZ_WD8 + SZ_Y);
  unsigned* rowmax = (unsigned*)(ws + SZ_X8 + SZ_WGU8 + SZ_WD8 + SZ_Y + SZ_YQ);

  // 1) pack int32 -> int8
  pack_i8<<<dim3(8192), dim3(256), 0, stream>>>((const int4*)x_q,  (char4*)x8,   (int)(SZ_X8 / 4));
  pack_i8<<<dim3(8192), dim3(256), 0, stream>>>((const int4*)w_gu, (char4*)wgu8, (int)(SZ_WGU8 / 4));
  pack_i8<<<dim3(8192), dim3(256), 0, stream>>>((const int4*)w_d,  (char4*)wd8,  (int)(SZ_WD8 / 4));
  zero_u32<<<dim3(16), dim3(256), 0, stream>>>(rowmax, T_DIM);

  // 2) fused GEMM1 + silu*up + row absmax  (128x128 tile, 86x32 grid)
  gemm1_silu<<<dim3(I_DIM / 128, T_DIM / 128), dim3(256), 0, stream>>>(
      x8, wgu8, x_scale, s_wgu, y, rowmax);

  // 3) dynamic per-row quantization
  quantize_y<<<dim3((unsigned)(((size_t)T_DIM * I_DIM / 4 + 255) / 256)), dim3(256), 0, stream>>>(
      y, rowmax, yq8);

  // 4) GEMM2 + scale epilogue  (128m x 256n tile, 16x32 grid)
  gemm2_scaled<<<dim3(H_DIM / 256, T_DIM / 128), dim3(256), 0, stream>>>(
      yq8, wd8, rowmax, s_wd, out);
}

// Round 9
// 1285.368 us; speedup vs baseline: 1.0679x; 1.0679x over previous
//
#include <hip/hip_runtime.h>
#include <cstdint>
#include <cstddef>

#define T_DIM 4096
#define H_DIM 4096
#define I_DIM 11008

typedef int v4i __attribute__((ext_vector_type(4)));

// ---------------------------------------------------------------------------
// async global->LDS copy, 16B per lane (global_load_lds_dwordx4)
// ---------------------------------------------------------------------------
__device__ __forceinline__ void async_copy16(const void* g, void* l) {
  __builtin_amdgcn_global_load_lds(
      (const __attribute__((address_space(1))) void*)g,
      (__attribute__((address_space(3))) void*)l, 16, 0, 0);
}

// ---------------------------------------------------------------------------
// fused prep: pack three int32 buffers -> int8 and zero rowmax, one launch
// (replaces 3 pack launches + zero launch; each region is a coalesced
// grid-stride loop, BW-bound)
// ---------------------------------------------------------------------------
__global__ void pack_all(const int4* __restrict__ xs,  char4* __restrict__ xd,  int nx4,
                         const int4* __restrict__ ws1, char4* __restrict__ wd1, int nw14,
                         const int4* __restrict__ ws2, char4* __restrict__ wd2, int nw24,
                         unsigned* __restrict__ rowmax, int nrm) {
  const int stride = gridDim.x * blockDim.x;
  const int t0 = blockIdx.x * blockDim.x + threadIdx.x;
  for (int i = t0; i < nrm; i += stride) rowmax[i] = 0u;
  for (int i = t0; i < nx4; i += stride) {
    int4 v = xs[i];
    char4 c; c.x = (char)v.x; c.y = (char)v.y; c.z = (char)v.z; c.w = (char)v.w;
    xd[i] = c;
  }
  for (int i = t0; i < nw14; i += stride) {
    int4 v = ws1[i];
    char4 c; c.x = (char)v.x; c.y = (char)v.y; c.z = (char)v.z; c.w = (char)v.w;
    wd1[i] = c;
  }
  for (int i = t0; i < nw24; i += stride) {
    int4 v = ws2[i];
    char4 c; c.x = (char)v.x; c.y = (char)v.y; c.z = (char)v.z; c.w = (char)v.w;
    wd2[i] = c;
  }
}

// ---------------------------------------------------------------------------
// GEMM1: gu = x_q @ w_gate_up^T (gate col n / up col I+n share the A tile),
// epilogue y = silu(gate)*up, per-row absmax via shfl + atomicMax.
// 128x128 tile, BK=64, 4 waves each 64x64 gate + 64x64 up, MFMA 16x16x64 i8
// (R8's 32x32 port regressed: 3.4e7 LDS bank conflicts -> reverted).
// m201-ordered phase: ds_read FIRST, then stage-issue, then MFMA cluster,
// then {vmcnt(6); s_barrier} at phase END. 3 buffers, depth-2 slack, vmcnt
// never 0 in-loop (T4). R6/R7-verified: 465 us, conflicts 0.
// ---------------------------------------------------------------------------
__global__ __launch_bounds__(256, 2)
void gemm1_silu(const int8_t* __restrict__ x8,
                const int8_t* __restrict__ wgu8,
                const float* __restrict__ x_scale,
                const float* __restrict__ s_wgu,
                float* __restrict__ y,
                unsigned* __restrict__ rowmax) {
  __shared__ __align__(16) char lds0[24576];
  __shared__ __align__(16) char lds1[24576];
  __shared__ __align__(16) char lds2[24576];

  const int tid = threadIdx.x;
  const int wave = tid >> 6, lane = tid & 63;
  const int wm = wave >> 1, wn = wave & 1;

  // Supertile XCD swizzle (R3, verified): 86x32 grid = 2752 blocks, 344/XCD.
  const unsigned bid = blockIdx.y * gridDim.x + blockIdx.x;
  const unsigned xcd = bid & 7;
  const unsigned l   = bid >> 3;        // 0..343
  const unsigned s   = l >> 5;          // supertile 0..10
  const unsigned r   = l - (s << 5);    // 0..31 (0..23 in the last)
  const int m0 = (int)(xcd * 4 + (r & 3)) * 128;
  const int n0 = (int)(s * 8 + (r >> 2)) * 128;

  v4i accg[4][4], accu[4][4];
  const v4i vzero = {0, 0, 0, 0};
#pragma unroll
  for (int i = 0; i < 4; i++)
#pragma unroll
    for (int j = 0; j < 4; j++) { accg[i][j] = vzero; accu[i][j] = vzero; }

  const int8_t* Ab  = x8 + (size_t)m0 * H_DIM;
  const int8_t* Bgb = wgu8 + (size_t)n0 * H_DIM;
  const int8_t* Bub = wgu8 + ((size_t)I_DIM + (size_t)n0) * H_DIM;

  // hoisted per-lane staging offsets (K-invariant)
  const int sr0 = wave * 16 + (lane >> 2);
  const int sr1 = (4 + wave) * 16 + (lane >> 2);
  const int sc0 = (lane & 3) ^ ((sr0 >> 1) & 3);
  const int sc1 = (lane & 3) ^ ((sr1 >> 1) & 3);
  const size_t vo0 = (size_t)sr0 * H_DIM + (size_t)sc0 * 16;
  const size_t vo1 = (size_t)sr1 * H_DIM + (size_t)sc1 * 16;
  const int ldsSeg0 = wave * 1024;
  const int ldsSeg1 = (4 + wave) * 1024;

  // hoisted per-lane fragment offsets (K-invariant)
  const int cfrag = ((lane >> 4) ^ (((lane & 15) >> 1) & 3)) * 16;
  const int aoff = (wm * 64 + (lane & 15)) * 64 + cfrag;  // + i*1024
  const int boff = (wn * 64 + (lane & 15)) * 64 + cfrag;  // + j*1024

#define G1_STAGE(L, T)                                                      \
  {                                                                         \
    const int8_t* A_ = Ab + ((size_t)(T) << 6);                             \
    const int8_t* G_ = Bgb + ((size_t)(T) << 6);                            \
    const int8_t* U_ = Bub + ((size_t)(T) << 6);                            \
    async_copy16(A_ + vo0, (L) + ldsSeg0);                                  \
    async_copy16(A_ + vo1, (L) + ldsSeg1);                                  \
    async_copy16(G_ + vo0, (L) + 8192 + ldsSeg0);                           \
    async_copy16(G_ + vo1, (L) + 8192 + ldsSeg1);                           \
    async_copy16(U_ + vo0, (L) + 16384 + ldsSeg0);                          \
    async_copy16(U_ + vo1, (L) + 16384 + ldsSeg1);                          \
  }

#define G1_PHASE(Lc, Ls, T2, DOSTAGE, VM)                                   \
  {                                                                         \
    v4i a[4], bg[4], bu[4];                                                 \
    _Pragma("unroll")                                                       \
    for (int i = 0; i < 4; i++) a[i]  = *(const v4i*)((Lc) + aoff + i * 1024);          \
    _Pragma("unroll")                                                       \
    for (int j = 0; j < 4; j++) bg[j] = *(const v4i*)((Lc) + 8192 + boff + j * 1024);   \
    _Pragma("unroll")                                                       \
    for (int j = 0; j < 4; j++) bu[j] = *(const v4i*)((Lc) + 16384 + boff + j * 1024);  \
    if (DOSTAGE) G1_STAGE(Ls, T2);                                          \
    __builtin_amdgcn_s_setprio(1);                                          \
    _Pragma("unroll")                                                       \
    for (int i = 0; i < 4; i++)                                             \
      _Pragma("unroll")                                                     \
      for (int j = 0; j < 4; j++) {                                         \
        accg[i][j] = __builtin_amdgcn_mfma_i32_16x16x64_i8(a[i], bg[j], accg[i][j], 0, 0, 0); \
        accu[i][j] = __builtin_amdgcn_mfma_i32_16x16x64_i8(a[i], bu[j], accu[i][j], 0, 0, 0); \
      }                                                                     \
    __builtin_amdgcn_s_setprio(0);                                          \
    asm volatile("s_waitcnt " VM ::: "memory");                             \
    __builtin_amdgcn_s_barrier();                                           \
  }

  G1_STAGE(lds0, 0);
  G1_STAGE(lds1, 1);
  asm volatile("s_waitcnt vmcnt(6)" ::: "memory");
  __builtin_amdgcn_s_barrier();

  // 64 K-tiles: phases 0..59 in-loop (20 x 3), 60..63 peeled with static VM.
  for (int t = 0; t < 60; t += 3) {
    G1_PHASE(lds0, lds2, t + 2, 1, "vmcnt(6)")
    G1_PHASE(lds1, lds0, t + 3, 1, "vmcnt(6)")
    G1_PHASE(lds2, lds1, t + 4, 1, "vmcnt(6)")
  }
  G1_PHASE(lds0, lds2, 62, 1, "vmcnt(6)")   // t=60
  G1_PHASE(lds1, lds0, 63, 1, "vmcnt(6)")   // t=61
  G1_PHASE(lds2, lds0,  0, 0, "vmcnt(0)")   // t=62: no stage, drain tile 63
  G1_PHASE(lds0, lds0,  0, 0, "vmcnt(0)")   // t=63: final
#undef G1_PHASE
#undef G1_STAGE

  // Epilogue. C/D layout (verified): col = lane&15, row = (lane>>4)*4 + reg.
  const int lr = lane >> 4;
  const int lc = lane & 15;
#pragma unroll
  for (int i = 0; i < 4; i++) {
#pragma unroll
    for (int t = 0; t < 4; t++) {
      const int gr = m0 + wm * 64 + i * 16 + lr * 4 + t;
      const float sx = x_scale[gr];
      float vmax = 0.f;
#pragma unroll
      for (int j = 0; j < 4; j++) {
        const int gc = n0 + wn * 64 + j * 16 + lc;
        float g = (float)accg[i][j][t] * sx * s_wgu[gc];
        float u = (float)accu[i][j][t] * sx * s_wgu[I_DIM + gc];
        float yv = (g / (1.f + expf(-g))) * u;   // silu(g) * u
        y[(size_t)gr * I_DIM + gc] = yv;
        vmax = fmaxf(vmax, fabsf(yv));
      }
#pragma unroll
      for (int off = 1; off < 16; off <<= 1)
        vmax = fmaxf(vmax, __shfl_xor(vmax, off, 64));
      if (lc == 0) atomicMax(&rowmax[gr], __float_as_uint(vmax));
    }
  }
}

// ---------------------------------------------------------------------------
// quantize y -> int8 with dynamic per-row scale s2 = max(|y|,1e-8)/127
// jnp.round == round-half-even == rintf; 32-bit const div -> magic multiply
// ---------------------------------------------------------------------------
__global__ void quantize_y(const float* __restrict__ y,
                           const unsigned* __restrict__ rowmax,
                           int8_t* __restrict__ yq) {
  const int N4 = (int)((size_t)T_DIM * I_DIM / 4);   // 11,272,192
  int gid = blockIdx.x * blockDim.x + threadIdx.x;
  if (gid >= N4) return;
  int row = gid / (I_DIM / 4);     // 32-bit const div -> magic multiply
  size_t base = (size_t)gid * 4;   // I_DIM % 4 == 0, packs never cross rows
  float inv = 127.f / fmaxf(__uint_as_float(rowmax[row]), 1e-8f);
  float4 v = *(const float4*)(y + base);
  char4 q;
  q.x = (char)(int)fminf(127.f, fmaxf(-128.f, rintf(v.x * inv)));
  q.y = (char)(int)fminf(127.f, fmaxf(-128.f, rintf(v.y * inv)));
  q.z = (char)(int)fminf(127.f, fmaxf(-128.f, rintf(v.z * inv)));
  q.w = (char)(int)fminf(127.f, fmaxf(-128.f, rintf(v.w * inv)));
  *(char4*)(yq + base) = q;
}

// ---------------------------------------------------------------------------
// GEMM2: out = (y_q @ w_down^T) * s2[row] * s_w_down[col]
// 128m x 256n tile (R7-verified), BK=64, MFMA 16x16x64 i8. Per wave
// 64m x 128n -> 4x8 frags, 32 MFMA/phase. Grid 512 blocks = 2/CU.
// Same counted-vmcnt(6) depth-2 pipeline.
// ---------------------------------------------------------------------------
__global__ __launch_bounds__(256, 2)
void gemm2_scaled(const int8_t* __restrict__ yq8,
                  const int8_t* __restrict__ wd8,
                  const unsigned* __restrict__ rowmax,
                  const float* __restrict__ s_wd,
                  float* __restrict__ out) {
  __shared__ __align__(16) char lds0[24576];
  __shared__ __align__(16) char lds1[24576];
  __shared__ __align__(16) char lds2[24576];

  const int tid = threadIdx.x;
  const int wave = tid >> 6, lane = tid & 63;
  const int wm = wave >> 1, wn = wave & 1;

  // XCD swizzle: grid = 16n x 32m = 512 blocks, 64/XCD = 4m x 16n.
  const unsigned bid = blockIdx.y * gridDim.x + blockIdx.x;
  const unsigned xcd = bid & 7;
  const unsigned l   = bid >> 3;            // 0..63
  const int m0 = (int)(xcd * 4 + (l & 3)) * 128;
  const int n0 = (int)(l >> 2) * 256;       // 0..15 * 256

  v4i acc[4][8];
  const v4i vzero = {0, 0, 0, 0};
#pragma unroll
  for (int i = 0; i < 4; i++)
#pragma unroll
    for (int j = 0; j < 8; j++) acc[i][j] = vzero;

  const int8_t* Ab = yq8 + (size_t)m0 * I_DIM;
  const int8_t* Bb = wd8 + (size_t)n0 * I_DIM;

  // staging offsets: A tile 128 rows (2 loads/lane, segs wave, wave+4),
  // B tile 256 rows (4 loads/lane, segs wave, wave+4, wave+8, wave+12).
  const int lrow = lane >> 2;
  const int lchk = lane & 3;
  int srA[2], srB[4];
  srA[0] = wave * 16 + lrow;        srA[1] = (4 + wave) * 16 + lrow;
#pragma unroll
  for (int q = 0; q < 4; q++) srB[q] = (q * 4 + wave) * 16 + lrow;
  size_t voA[2], voB[4];
#pragma unroll
  for (int q = 0; q < 2; q++)
    voA[q] = (size_t)srA[q] * I_DIM + (size_t)(lchk ^ ((srA[q] >> 1) & 3)) * 16;
#pragma unroll
  for (int q = 0; q < 4; q++)
    voB[q] = (size_t)srB[q] * I_DIM + (size_t)(lchk ^ ((srB[q] >> 1) & 3)) * 16;
  const int segA0 = wave * 1024, segA1 = (4 + wave) * 1024;

  const int cfrag = ((lane >> 4) ^ (((lane & 15) >> 1) & 3)) * 16;
  const int aoff = (wm * 64 + (lane & 15)) * 64 + cfrag;    // + i*1024, i<4
  const int boff = (wn * 128 + (lane & 15)) * 64 + cfrag;   // + j*1024, j<8

#define G2_STAGE(L, T)                                                      \
  {                                                                         \
    const int8_t* A_ = Ab + ((size_t)(T) << 6);                             \
    const int8_t* B_ = Bb + ((size_t)(T) << 6);                             \
    async_copy16(A_ + voA[0], (L) + segA0);                                 \
    async_copy16(A_ + voA[1], (L) + segA1);                                 \
    async_copy16(B_ + voB[0], (L) + 8192 + segA0);                          \
    async_copy16(B_ + voB[1], (L) + 8192 + segA1);                          \
    async_copy16(B_ + voB[2], (L) + 8192 + segA0 + 8192);                   \
    async_copy16(B_ + voB[3], (L) + 8192 + segA1 + 8192);                   \
  }

#define G2_PHASE(Lc, Ls, T2, DOSTAGE, VM)                                   \
  {                                                                         \
    v4i a[4], b[8];                                                         \
    _Pragma("unroll")                                                       \
    for (int i = 0; i < 4; i++) a[i] = *(const v4i*)((Lc) + aoff + i * 1024);        \
    _Pragma("unroll")                                                       \
    for (int j = 0; j < 8; j++) b[j] = *(const v4i*)((Lc) + 8192 + boff + j * 1024); \
    if (DOSTAGE) G2_STAGE(Ls, T2);                                          \
    __builtin_amdgcn_s_setprio(1);                                          \
    _Pragma("unroll")                                                       \
    for (int i = 0; i < 4; i++)                                             \
      _Pragma("unroll")                                                     \
      for (int j = 0; j < 8; j++)                                           \
        acc[i][j] = __builtin_amdgcn_mfma_i32_16x16x64_i8(a[i], b[j], acc[i][j], 0, 0, 0); \
    __builtin_amdgcn_s_setprio(0);                                          \
    asm volatile("s_waitcnt " VM ::: "memory");                             \
    __builtin_amdgcn_s_barrier();                                           \
  }

  G2_STAGE(lds0, 0);
  G2_STAGE(lds1, 1);
  asm volatile("s_waitcnt vmcnt(6)" ::: "memory");
  __builtin_amdgcn_s_barrier();

  // 172 K-tiles: phases 0..167 in-loop (56 x 3), 168..171 peeled.
  for (int t = 0; t < 168; t += 3) {
    G2_PHASE(lds0, lds2, t + 2, 1, "vmcnt(6)")
    G2_PHASE(lds1, lds0, t + 3, 1, "vmcnt(6)")
    G2_PHASE(lds2, lds1, t + 4, 1, "vmcnt(6)")
  }
  G2_PHASE(lds0, lds2, 170, 1, "vmcnt(6)")  // t=168
  G2_PHASE(lds1, lds0, 171, 1, "vmcnt(6)")  // t=169
  G2_PHASE(lds2, lds0,   0, 0, "vmcnt(0)")  // t=170: drain tile 171
  G2_PHASE(lds0, lds0,   0, 0, "vmcnt(0)")  // t=171: final
#undef G2_PHASE
#undef G2_STAGE

  const int lr = lane >> 4;
  const int lc = lane & 15;
#pragma unroll
  for (int i = 0; i < 4; i++) {
#pragma unroll
    for (int t = 0; t < 4; t++) {
      const int gr = m0 + wm * 64 + i * 16 + lr * 4 + t;
      const float s2 = fmaxf(__uint_as_float(rowmax[gr]), 1e-8f) / 127.f;
#pragma unroll
      for (int j = 0; j < 8; j++) {
        const int gc = n0 + wn * 128 + j * 16 + lc;
        out[(size_t)gr * H_DIM + gc] = (float)acc[i][j][t] * s2 * s_wd[gc];
      }
    }
  }
}

// ---------------------------------------------------------------------------
// launch
// ---------------------------------------------------------------------------
extern "C" void kernel_launch(void* const* d_in, const int* in_sizes, int n_in,
                              void* d_out, int out_size, void* d_ws, size_t ws_size,
                              hipStream_t stream) {
  const int*   x_q     = (const int*)d_in[0];
  const float* x_scale = (const float*)d_in[1];
  const int*   w_gu    = (const int*)d_in[2];
  const float* s_wgu   = (const float*)d_in[3];
  const int*   w_d     = (const int*)d_in[4];
  const float* s_wd    = (const float*)d_in[5];
  float* out = (float*)d_out;

  // workspace layout (bytes)
  char* ws = (char*)d_ws;
  const size_t SZ_X8   = (size_t)T_DIM * H_DIM;          //  16,777,216
  const size_t SZ_WGU8 = (size_t)2 * I_DIM * H_DIM;      //  90,177,536
  const size_t SZ_WD8  = (size_t)H_DIM * I_DIM;          //  45,088,768
  const size_t SZ_Y    = (size_t)T_DIM * I_DIM * 4;      // 180,355,072
  const size_t SZ_YQ   = (size_t)T_DIM * I_DIM;          //  45,088,768

  int8_t*   x8     = (int8_t*)ws;
  int8_t*   wgu8   = (int8_t*)(ws + SZ_X8);
  int8_t*   wd8    = (int8_t*)(ws + SZ_X8 + SZ_WGU8);
  float*    y      = (float*)(ws + SZ_X8 + SZ_WGU8 + SZ_WD8);
  int8_t*   yq8    = (int8_t*)(ws + SZ_X8 + SZ_WGU8 + SZ_WD8 + SZ_Y);
  unsigned* rowmax = (unsigned*)(ws + SZ_X8 + SZ_WGU8 + SZ_WD8 + SZ_Y + SZ_YQ);

  // 1) fused pack int32 -> int8 (x, w_gate_up, w_down) + rowmax zero
  pack_all<<<dim3(8192), dim3(256), 0, stream>>>(
      (const int4*)x_q,  (char4*)x8,   (int)(SZ_X8 / 4),
      (const int4*)w_gu, (char4*)wgu8, (int)(SZ_WGU8 / 4),
      (const int4*)w_d,  (char4*)wd8,  (int)(SZ_WD8 / 4),
      rowmax, T_DIM);

  // 2) fused GEMM1 + silu*up + row absmax  (128x128 tile, 86x32 grid)
  gemm1_silu<<<dim3(I_DIM / 128, T_DIM / 128), dim3(256), 0, stream>>>(
      x8, wgu8, x_scale, s_wgu, y, rowmax);

  // 3) dynamic per-row quantization
  quantize_y<<<dim3((unsigned)(((size_t)T_DIM * I_DIM / 4 + 255) / 256)), dim3(256), 0, stream>>>(
      y, rowmax, yq8);

  // 4) GEMM2 + scale epilogue  (128m x 256n tile, 16x32 grid)
  gemm2_scaled<<<dim3(H_DIM / 256, T_DIM / 128), dim3(256), 0, stream>>>(
      yq8, wd8, rowmax, s_wd, out);
}